// Round 11
// baseline (21.846 us; speedup 1.0000x reference)
//
#include <hip/hip_runtime.h>

// Problem constants (fixed by the reference)
#define NTOT 512   // N
#define NH   448   // N - K (identity head)
#define KK   64    // K (solved tail rows)
#define NL   30688 // strictly-lower entries in last K rows
#define DD   16    // domains

// ws layout (floats):
//   Tp[dom][r][c]: dom*28672 + r*448 + c   (rows 1792B, 16B-aligned)
//   Up[dom][r][m]: UPOFF + dom*4096 + r*64 + m  (zero-padded square)
#define TP_STRIDE 28672          // 64*448
#define UPOFF     (DD * TP_STRIDE)   // 458752 floats = 1835008 B
#define UP_STRIDE 4096           // 64*64
// total ws use: (458752 + 65536) * 4 = 2,097,152 B

// z = F_d eps, F_d = (I-L)^{-1} S  <=>  (I-L) z = S eps.
// Head: z_j = eps_j + bias_sh.  Tail r: y_r = s_r*eps_{448+r} + T_r.eps[0:448];
// z_tail = (I-U)^{-1} y (63-step wave solve).
// r11: L_emb's triangular packing makes T-row starts only 4B-aligned -> phase 2
// was 112 scalar VMEM/wave (the r10 limiter). Repack T/U once (chain-free pure
// copy, fully parallel) into aligned ws, then phase 2 = 2 float4 loads/row.

// ---------- Kernel P: repack T and U into aligned ws ----------
__global__ __launch_bounds__(256)
void fvae_repack(const float* __restrict__ L_emb, float* __restrict__ ws)
{
    const int dom  = blockIdx.x >> 3;    // 16 doms x 8 parts
    const int part = blockIdx.x & 7;
    const int tid  = threadIdx.x;
    if (dom == 0) return;                // apply never reads dom 0

    const float* __restrict__ Ld = L_emb + (size_t)dom * NL;
    float* __restrict__ Tp = ws + (size_t)dom * TP_STRIDE;
    float* __restrict__ Up = ws + UPOFF + (size_t)dom * UP_STRIDE;

    // T copy: dst linear i = r*448+c; src = i + r(r-1)/2 (coalesced per row)
    for (int i = part * 3584 + tid; i < (part + 1) * 3584 + (part == 7 ? 0 : 0); i += 256) {
        const int r = i / 448;
        Tp[i] = Ld[i + (r * (r - 1)) / 2];
    }
    // full coverage check: 8 parts * 3584 = 28672 ✓

    // U copy with zero-pad: 4096 elems, 512 per part
    for (int i = part * 512 + tid; i < (part + 1) * 512; i += 256) {
        const int r = i >> 6, m = i & 63;
        Up[i] = (m < r) ? Ld[r * NH + (r * (r - 1)) / 2 + NH + m] : 0.f;
    }
}

// ---------- Kernel F: one block per sample (r9/r10-proven shape) ----------
__global__ __launch_bounds__(256)
void fvae_fused(const float* __restrict__ eps,      // [B,512]
                const int*   __restrict__ dom_idx,  // [B]
                const float* __restrict__ ws,       // Tp/Up
                const float* __restrict__ S_emb,    // [16, 64]
                const float* __restrict__ bias_ns,  // [16, 64]
                const float* __restrict__ bias_sh,  // [448]
                float*       __restrict__ out)      // [B,512]
{
    const int b    = blockIdx.x;
    const int tid  = threadIdx.x;
    const int wave = tid >> 6;
    const int lane = tid & 63;

    __shared__ float y_s[KK];
    __shared__ float U_s[KK][KK + 1];   // padded: phase-3 reads 2-way (free)

    const int dom = dom_idx[b];
    const float* __restrict__ epsb = eps + (size_t)b * NTOT;
    float*       __restrict__ outb = out + (size_t)b * NTOT;

    if (dom == 0) {
        // L=0, S=I: out = eps + [bias_sh | bias_ns]
        if (tid < 128) {
            const float4 e = *(const float4*)(epsb + tid * 4);
            float4 bv;
            if (tid < 112) bv = *(const float4*)(bias_sh + tid * 4);
            else           bv = *(const float4*)(bias_ns + (tid - 112) * 4);
            float4 o; o.x = e.x + bv.x; o.y = e.y + bv.y;
            o.z = e.z + bv.z; o.w = e.w + bv.w;
            *(float4*)(outb + tid * 4) = o;
        }
        return;
    }

    const float* __restrict__ Tp = ws + (size_t)dom * TP_STRIDE;
    const float* __restrict__ Up = ws + UPOFF + (size_t)dom * UP_STRIDE;

    // ---- eps quads to registers (issued early; consumed after barrier)
    const float4 ea = *(const float4*)(epsb + lane * 4);                 // j 0..255
    float4 eb = make_float4(0.f, 0.f, 0.f, 0.f);
    if (lane < 48) eb = *(const float4*)(epsb + 256 + lane * 4);         // j 256..447

    if (wave == 0) {
        // head write overlaps U staging (112 float4 over 64 lanes)
        for (int q = lane; q < NH / 4; q += 64) {
            const float4 e  = *(const float4*)(epsb + q * 4);
            const float4 bs = *(const float4*)(bias_sh + q * 4);
            float4 o; o.x = e.x + bs.x; o.y = e.y + bs.y;
            o.z = e.z + bs.z; o.w = e.w + bs.w;
            *(float4*)(outb + q * 4) = o;
        }
    } else {
        // waves 1-3 stage U: 1024 float4 over 192 threads, coalesced
        const int t2 = tid - 64;
        for (int i = t2; i < 1024; i += 192) {
            const float4 v = *(const float4*)(Up + i * 4);
            const int r = i >> 4, m = (i & 15) * 4;
            U_s[r][m] = v.x; U_s[r][m + 1] = v.y;
            U_s[r][m + 2] = v.z; U_s[r][m + 3] = v.w;
        }
    }
    __syncthreads();

    // ---- phase 2: wave owns rows [wave*16,+16); 2 float4 loads per row
    #pragma unroll
    for (int bt = 0; bt < 4; ++bt) {
        const int r0 = wave * 16 + bt * 4;
        float a0, a1, a2, a3;
        {
            const float4* __restrict__ T0 = (const float4*)(Tp + (r0    ) * 448);
            const float4* __restrict__ T1 = (const float4*)(Tp + (r0 + 1) * 448);
            const float4* __restrict__ T2 = (const float4*)(Tp + (r0 + 2) * 448);
            const float4* __restrict__ T3 = (const float4*)(Tp + (r0 + 3) * 448);
            const float4 p0 = T0[lane], p1 = T1[lane], p2 = T2[lane], p3 = T3[lane];
            a0 = p0.x*ea.x + p0.y*ea.y + p0.z*ea.z + p0.w*ea.w;
            a1 = p1.x*ea.x + p1.y*ea.y + p1.z*ea.z + p1.w*ea.w;
            a2 = p2.x*ea.x + p2.y*ea.y + p2.z*ea.z + p2.w*ea.w;
            a3 = p3.x*ea.x + p3.y*ea.y + p3.z*ea.z + p3.w*ea.w;
            if (lane < 48) {
                const float4 q0 = T0[64 + lane], q1 = T1[64 + lane],
                             q2 = T2[64 + lane], q3 = T3[64 + lane];
                a0 += q0.x*eb.x + q0.y*eb.y + q0.z*eb.z + q0.w*eb.w;
                a1 += q1.x*eb.x + q1.y*eb.y + q1.z*eb.z + q1.w*eb.w;
                a2 += q2.x*eb.x + q2.y*eb.y + q2.z*eb.z + q2.w*eb.w;
                a3 += q3.x*eb.x + q3.y*eb.y + q3.z*eb.z + q3.w*eb.w;
            }
        }
        // merged butterfly reduce (r4-verified): lane g<4 holds sum of a_g
        a0 += __shfl_xor(a0, 1);  a1 += __shfl_xor(a1, 1);
        a2 += __shfl_xor(a2, 1);  a3 += __shfl_xor(a3, 1);
        float c0 = (lane & 1) ? a1 : a0;
        float c1 = (lane & 1) ? a3 : a2;
        c0 += __shfl_xor(c0, 2);  c1 += __shfl_xor(c1, 2);
        float dsum = (lane & 2) ? c1 : c0;
        dsum += __shfl_xor(dsum, 4);
        dsum += __shfl_xor(dsum, 8);
        dsum += __shfl_xor(dsum, 16);
        dsum += __shfl_xor(dsum, 32);
        if (lane < 4) {
            const int r = r0 + lane;
            y_s[r] = dsum + S_emb[dom * KK + r] * epsb[NH + r];
        }
    }
    __syncthreads();

    // ---- phase 3: wave 0; padded U_s reads are 2-way (free), chain-independent
    if (wave == 0) {
        const int m = lane;
        float z = y_s[m];
        #pragma unroll
        for (int r = 0; r < KK - 1; ++r) {
            const float u = (r < m) ? U_s[m][r] : 0.f;
            z += u * __shfl(z, r);               // lane r's z final by step r
        }
        outb[NH + m] = z + bias_ns[dom * KK + m];
    }
}

extern "C" void kernel_launch(void* const* d_in, const int* in_sizes, int n_in,
                              void* d_out, int out_size, void* d_ws, size_t ws_size,
                              hipStream_t stream) {
    const float* eps     = (const float*)d_in[0];
    const int*   dom     = (const int*)  d_in[1];
    const float* L_emb   = (const float*)d_in[2];
    const float* S_emb   = (const float*)d_in[3];
    const float* bias_ns = (const float*)d_in[4];
    const float* bias_sh = (const float*)d_in[5];
    float* out = (float*)d_out;
    float* ws  = (float*)d_ws;

    const int B = in_sizes[0] / NTOT;   // 1024
    fvae_repack<<<dim3(DD * 8), dim3(256), 0, stream>>>(L_emb, ws);
    fvae_fused <<<dim3(B),      dim3(256), 0, stream>>>(eps, dom, ws, S_emb,
                                                        bias_ns, bias_sh, out);
}